// Round 11
// baseline (37.932 us; speedup 1.0000x reference)
//
#include <hip/hip_runtime.h>
#include <cstdint>
#include <cstddef>

// Problem constants
constexpr int B_  = 256;
constexpr int N_  = 16354;
constexpr int M_  = 512;
constexpr int V_  = 4096;
constexpr int S_  = 32;     // stride of the strided convs
constexpr int G3  = 1536;   // 3*M

// ---------------------------------------------------------------------------
// Kernel 1: front end. One block per batch row, 512 threads (one per output j).
// ---------------------------------------------------------------------------
__global__ __launch_bounds__(512) void k_front(
    const float* __restrict__ st1, const float* __restrict__ ht1,
    const float* __restrict__ zt, const int* __restrict__ da_t,
    const float* __restrict__ w_st1, const float* __restrict__ b_st1,
    const float* __restrict__ w_st12, const float* __restrict__ b_st12,
    const float* __restrict__ w_mt1, const float* __restrict__ b_mt1,
    const float* __restrict__ w_xt, const float* __restrict__ b_xt,
    float* __restrict__ xt_out, float* __restrict__ ht1c_out)
{
    __shared__ float sm[2 * M_];   // Mt1 = [Mt1_0 | ht1]
    const int b = blockIdx.x;
    const int j = threadIdx.x;

    const float* srow = st1 + (size_t)b * N_;

    const float w0 = w_st1[0], w1 = w_st1[1], w2 = w_st1[2], w3 = w_st1[3], w4 = w_st1[4];
    const float bs = b_st1[0];

    // conv5 (pad 2) evaluated at p = 32j and p+1 -> needs st1[p-2 .. p+3]
    const int p = S_ * j;
    float x[6];
    if (j > 0 && j < M_ - 1) {
        const float2 a = *(const float2*)(srow + p - 2);
        const float2 c = *(const float2*)(srow + p);
        const float2 d = *(const float2*)(srow + p + 2);
        x[0] = a.x; x[1] = a.y; x[2] = c.x; x[3] = c.y; x[4] = d.x; x[5] = d.y;
    } else {
        #pragma unroll
        for (int k = 0; k < 6; ++k) {
            int ix = p - 2 + k;
            x[k] = (ix >= 0 && ix < N_) ? srow[ix] : 0.0f;
        }
    }
    float y0 = bs;
    y0 = fmaf(x[0], w0, y0); y0 = fmaf(x[1], w1, y0); y0 = fmaf(x[2], w2, y0);
    y0 = fmaf(x[3], w3, y0); y0 = fmaf(x[4], w4, y0);
    float y1 = bs;
    y1 = fmaf(x[1], w0, y1); y1 = fmaf(x[2], w1, y1); y1 = fmaf(x[3], w2, y1);
    y1 = fmaf(x[4], w3, y1); y1 = fmaf(x[5], w4, y1);

    const float m0 = fmaf(y0, w_st12[0], fmaf(y1, w_st12[1], b_st12[0]));
    sm[j]      = m0;
    sm[M_ + j] = ht1[(size_t)b * M_ + j];

    const float daf = (float)da_t[b];
    const float* zrow = zt + (size_t)b * (N_ - 1);
    const float u0 = zrow[S_ * j];
    const float u1 = (j == M_ - 1) ? daf : zrow[S_ * j + 1];
    xt_out[(size_t)b * M_ + j] = fmaf(u0, w_xt[0], fmaf(u1, w_xt[1], b_xt[0]));

    __syncthreads();

    const int q = 2 * j;
    float vm1 = 0.0f, v0, vp1 = 0.0f;
    if (q - 1 >= 0) { float t = sm[q - 1]; vm1 = t > 0.0f ? t : 0.0f; }
    { float t = sm[q]; v0 = t > 0.0f ? t : 0.0f; }
    if (q + 1 < 2 * M_) { float t = sm[q + 1]; vp1 = t > 0.0f ? t : 0.0f; }
    const float hv = fmaf(vm1, w_mt1[0], fmaf(v0, w_mt1[1], fmaf(vp1, w_mt1[2], b_mt1[0])));
    ht1c_out[(size_t)b * M_ + j] = hv;
}

// ---------------------------------------------------------------------------
// Kernel 2: f32 GEMM (R3 tile), K-split zs for occupancy.
// R9 PMC: VALUBusy 41%, Occ 14% at 384 blocks (latency-bound). zs=4 -> 36.8us.
// zs=8 -> 1536 blocks = 6 blocks/CU = 24 waves/CU (LDS 104KB/CU, VGPR 40).
// BM=64 x BN=64 x BK=32, 256 threads, 4x4 frag, both fragments ds_read_b128.
// Partials g[z][which][B][G3] summed in the tail in fixed z-order.
// ---------------------------------------------------------------------------
constexpr int BMt = 64;
constexpr int BNt = 64;
constexpr int BKt = 32;
constexpr size_t GPART = (size_t)B_ * G3;   // elements per partial matrix

__global__ __launch_bounds__(256) void k_gemm(
    const float* __restrict__ xt, const float* __restrict__ Ht1c,
    const float* __restrict__ W_ih, const float* __restrict__ W_hh,
    float* __restrict__ g, int kper)
{
    __shared__ __align__(16) float As[BKt][BMt + 4];  // row = 272B (17x16B)
    __shared__ __align__(16) float Ws[BKt][BNt + 4];

    const int t = threadIdx.x;
    const int bm0 = blockIdx.y * BMt;
    const int z = blockIdx.z;
    int n0 = blockIdx.x * BNt;

    const float* A;
    const float* W;
    float* out;
    if (n0 < G3) { A = xt;   W = W_ih; out = g + (size_t)(2 * z + 0) * GPART; }
    else         { A = Ht1c; W = W_hh; out = g + (size_t)(2 * z + 1) * GPART; n0 -= G3; }

    // staging coords: 64 rows x 32 k per tile, 2 float4 per thread
    const int srow = t >> 2;          // 0..63
    const int sc4  = t & 3;           // 0..3 (k-chunk)

    // fragment coords
    const int tm = (t & 15) * 4;      // 4 batch rows
    const int tn = (t >> 4) * 4;      // 4 output cols

    float acc[4][4];
    #pragma unroll
    for (int i = 0; i < 4; ++i)
        #pragma unroll
        for (int jj = 0; jj < 4; ++jj) acc[i][jj] = 0.0f;

    const int kbeg = z * kper;
    const int kend = kbeg + kper;

    for (int k0 = kbeg; k0 < kend; k0 += BKt) {
        {
            const float* ap = A + (size_t)(bm0 + srow) * M_ + k0 + 4 * sc4;
            const float4 f0 = *(const float4*)ap;
            const float4 f1 = *(const float4*)(ap + 16);
            As[4 * sc4 + 0][srow] = f0.x; As[4 * sc4 + 1][srow] = f0.y;
            As[4 * sc4 + 2][srow] = f0.z; As[4 * sc4 + 3][srow] = f0.w;
            As[16 + 4 * sc4 + 0][srow] = f1.x; As[16 + 4 * sc4 + 1][srow] = f1.y;
            As[16 + 4 * sc4 + 2][srow] = f1.z; As[16 + 4 * sc4 + 3][srow] = f1.w;
        }
        {
            const float* wp = W + (size_t)(n0 + srow) * M_ + k0 + 4 * sc4;
            const float4 g0 = *(const float4*)wp;
            const float4 g1 = *(const float4*)(wp + 16);
            Ws[4 * sc4 + 0][srow] = g0.x; Ws[4 * sc4 + 1][srow] = g0.y;
            Ws[4 * sc4 + 2][srow] = g0.z; Ws[4 * sc4 + 3][srow] = g0.w;
            Ws[16 + 4 * sc4 + 0][srow] = g1.x; Ws[16 + 4 * sc4 + 1][srow] = g1.y;
            Ws[16 + 4 * sc4 + 2][srow] = g1.z; Ws[16 + 4 * sc4 + 3][srow] = g1.w;
        }
        __syncthreads();

        #pragma unroll
        for (int k = 0; k < BKt; ++k) {
            const float4 a = *(const float4*)&As[k][tm];   // ds_read_b128
            const float4 w = *(const float4*)&Ws[k][tn];   // ds_read_b128
            acc[0][0] = fmaf(a.x, w.x, acc[0][0]); acc[0][1] = fmaf(a.x, w.y, acc[0][1]);
            acc[0][2] = fmaf(a.x, w.z, acc[0][2]); acc[0][3] = fmaf(a.x, w.w, acc[0][3]);
            acc[1][0] = fmaf(a.y, w.x, acc[1][0]); acc[1][1] = fmaf(a.y, w.y, acc[1][1]);
            acc[1][2] = fmaf(a.y, w.z, acc[1][2]); acc[1][3] = fmaf(a.y, w.w, acc[1][3]);
            acc[2][0] = fmaf(a.z, w.x, acc[2][0]); acc[2][1] = fmaf(a.z, w.y, acc[2][1]);
            acc[2][2] = fmaf(a.z, w.z, acc[2][2]); acc[2][3] = fmaf(a.z, w.w, acc[2][3]);
            acc[3][0] = fmaf(a.w, w.x, acc[3][0]); acc[3][1] = fmaf(a.w, w.y, acc[3][1]);
            acc[3][2] = fmaf(a.w, w.z, acc[3][2]); acc[3][3] = fmaf(a.w, w.w, acc[3][3]);
        }
        __syncthreads();
    }

    #pragma unroll
    for (int i = 0; i < 4; ++i) {
        float4 o;
        o.x = acc[i][0]; o.y = acc[i][1]; o.z = acc[i][2]; o.w = acc[i][3];
        *(float4*)&out[(size_t)(bm0 + tm + i) * G3 + n0 + tn] = o;  // 16B-aligned
    }
}

// ---------------------------------------------------------------------------
// Kernel 3 (fused tail): GRU gates + ht + it/ct reductions, then the row
// stream st[b,i] = (da+i < N ? st1[b, da+i] : 0)*ct + emb[it, i].
// One block per batch row, 1024 threads. Partial-sum accumulation is split:
// threads 0..511 sum the gi partials, threads 512..1023 sum the gh partials
// into LDS (halves the serial load prefix at zs=8: 24 loads/thread not 48).
// g layout: [z][which][B][G3]; fixed z-order, deterministic.
// ---------------------------------------------------------------------------
__global__ __launch_bounds__(1024) void k_tail(
    const float* __restrict__ g, int zs,
    const float* __restrict__ b_ih, const float* __restrict__ b_hh,
    const float* __restrict__ Ht1c, const int* __restrict__ da_t,
    const float* __restrict__ w_lht, const float* __restrict__ b_lht,
    const float* __restrict__ w_lct, const float* __restrict__ b_lct,
    const float* __restrict__ st1, const float* __restrict__ emb,
    float* __restrict__ ht_out, float* __restrict__ st_out)
{
    __shared__ float shh[3][M_];     // hr, hz, hn partial sums from upper half
    __shared__ float red1[8], red2[8];
    __shared__ float s_ct;
    __shared__ int   s_it;

    const int b = blockIdx.x;
    const int o = threadIdx.x;
    const int da = da_t[b];

    float ir = 0.f, iz = 0.f, inn = 0.f;
    if (o < M_) {
        // lower half: gi partials (which=0), fixed z-order
        for (int zz = 0; zz < zs; ++zz) {
            const float* gib = g + (size_t)(2 * zz + 0) * GPART + (size_t)b * G3;
            ir  += gib[o];
            iz  += gib[M_ + o];
            inn += gib[2 * M_ + o];
        }
    } else {
        // upper half: gh partials (which=1), fixed z-order
        const int o2 = o - M_;
        float hr = 0.f, hz = 0.f, hn = 0.f;
        for (int zz = 0; zz < zs; ++zz) {
            const float* ghb = g + (size_t)(2 * zz + 1) * GPART + (size_t)b * G3;
            hr += ghb[o2];
            hz += ghb[M_ + o2];
            hn += ghb[2 * M_ + o2];
        }
        shh[0][o2] = hr; shh[1][o2] = hz; shh[2][o2] = hn;
    }
    __syncthreads();

    if (o < M_) {
        ir  += b_ih[o];
        iz  += b_ih[M_ + o];
        inn += b_ih[2 * M_ + o];
        const float hr = shh[0][o] + b_hh[o];
        const float hz = shh[1][o] + b_hh[M_ + o];
        const float hn = shh[2][o] + b_hh[2 * M_ + o];

        const float r  = 1.0f / (1.0f + expf(-(ir + hr)));
        const float z  = 1.0f / (1.0f + expf(-(iz + hz)));
        const float n_ = tanhf(fmaf(r, hn, inn));
        const float hprev = Ht1c[(size_t)b * M_ + o];
        const float h = (1.0f - z) * n_ + z * hprev;

        ht_out[(size_t)b * M_ + o] = h;

        float p1 = h * w_lht[o];
        float p2 = h * w_lct[o];
        #pragma unroll
        for (int off = 32; off > 0; off >>= 1) {
            p1 += __shfl_down(p1, off);
            p2 += __shfl_down(p2, off);
        }
        const int wid = o >> 6, lane = o & 63;
        if (lane == 0) { red1[wid] = p1; red2[wid] = p2; }
    }
    __syncthreads();
    if (o == 0) {
        float s1 = 0.0f, s2 = 0.0f;
        #pragma unroll
        for (int i = 0; i < 8; ++i) { s1 += red1[i]; s2 += red2[i]; }
        const float a1 = s1 + b_lht[0];
        const float sg1 = 1.0f / (1.0f + expf(-a1));
        s_it = (int)floorf((float)(V_ - 1) * sg1);

        const float daf = (float)da;
        const float a2 = s2 + daf * w_lct[M_] + b_lct[0];
        s_ct = 1.0f / (1.0f + expf(-a2));
    }
    __syncthreads();

    const int   it = s_it;
    const float ct = s_ct;

    const float* er = emb + (size_t)it * N_;
    const float* sr = st1 + (size_t)b * N_;
    float* orow     = st_out + (size_t)b * N_;

    // float2 streaming: N even (8177 pairs); rows 8B-aligned.
    const float2* er2 = (const float2*)er;
    float2* orow2     = (float2*)orow;
    constexpr int H = N_ / 2;

    if ((da & 1) == 0) {
        for (int k = o; k < H; k += 1024) {
            const int i = 2 * k;
            const int idx = da + i;
            float2 sv;
            if (idx + 1 < N_)      sv = *(const float2*)(sr + idx);
            else if (idx < N_)     { sv.x = sr[idx]; sv.y = 0.0f; }
            else                   { sv.x = 0.0f; sv.y = 0.0f; }
            const float2 e = er2[k];
            float2 ov;
            ov.x = fmaf(sv.x, ct, e.x);
            ov.y = fmaf(sv.y, ct, e.y);
            orow2[k] = ov;
        }
    } else {
        for (int k = o; k < H; k += 1024) {
            const int i = 2 * k;
            const int idx = da + i;
            float2 sv;
            sv.x = (idx < N_)     ? sr[idx]     : 0.0f;
            sv.y = (idx + 1 < N_) ? sr[idx + 1] : 0.0f;
            const float2 e = er2[k];
            float2 ov;
            ov.x = fmaf(sv.x, ct, e.x);
            ov.y = fmaf(sv.y, ct, e.y);
            orow2[k] = ov;
        }
    }
}

// ---------------------------------------------------------------------------
extern "C" void kernel_launch(void* const* d_in, const int* in_sizes, int n_in,
                              void* d_out, int out_size, void* d_ws, size_t ws_size,
                              hipStream_t stream)
{
    const float* st1   = (const float*)d_in[0];
    const float* ht1   = (const float*)d_in[1];
    const float* zt    = (const float*)d_in[2];
    const int*   da_t  = (const int*)d_in[3];
    const float* w_st1 = (const float*)d_in[4];
    const float* b_st1 = (const float*)d_in[5];
    const float* w_st12= (const float*)d_in[6];
    const float* b_st12= (const float*)d_in[7];
    const float* w_mt1 = (const float*)d_in[8];
    const float* b_mt1 = (const float*)d_in[9];
    const float* w_xt  = (const float*)d_in[10];
    const float* b_xt  = (const float*)d_in[11];
    const float* W_ih  = (const float*)d_in[12];
    const float* W_hh  = (const float*)d_in[13];
    const float* b_ih  = (const float*)d_in[14];
    const float* b_hh  = (const float*)d_in[15];
    const float* w_lht = (const float*)d_in[16];
    const float* b_lht = (const float*)d_in[17];
    const float* w_lct = (const float*)d_in[18];
    const float* b_lct = (const float*)d_in[19];
    const float* emb   = (const float*)d_in[20];

    float* st_out = (float*)d_out;                      // [B, N]
    float* ht_out = (float*)d_out + (size_t)B_ * N_;    // [B, M]

    // workspace layout (floats): xt, Ht1c, g[z][2][B][G3]
    float* ws   = (float*)d_ws;
    float* xt   = ws;                         // B*M
    float* Ht1c = xt + (size_t)B_ * M_;       // B*M
    float* g    = Ht1c + (size_t)B_ * M_;     // zs*2*B*G3

    const size_t base = 2 * (size_t)B_ * M_ * sizeof(float);
    int zs = 1;
    if (ws_size >= base + 16 * GPART * sizeof(float))     zs = 8;
    else if (ws_size >= base + 8 * GPART * sizeof(float)) zs = 4;
    else if (ws_size >= base + 4 * GPART * sizeof(float)) zs = 2;
    const int kper = M_ / zs;

    k_front<<<dim3(B_), dim3(M_), 0, stream>>>(
        st1, ht1, zt, da_t, w_st1, b_st1, w_st12, b_st12,
        w_mt1, b_mt1, w_xt, b_xt, xt, Ht1c);

    k_gemm<<<dim3(2 * G3 / BNt, B_ / BMt, zs), dim3(256), 0, stream>>>(
        xt, Ht1c, W_ih, W_hh, g, kper);

    k_tail<<<dim3(B_), dim3(1024), 0, stream>>>(
        g, zs, b_ih, b_hh, Ht1c, da_t,
        w_lht, b_lht, w_lct, b_lct, st1, emb, ht_out, st_out);
}

// Round 12
// 36.303 us; speedup vs baseline: 1.0449x; 1.0449x over previous
//
#include <hip/hip_runtime.h>
#include <cstdint>
#include <cstddef>

// Problem constants
constexpr int B_  = 256;
constexpr int N_  = 16354;
constexpr int M_  = 512;
constexpr int V_  = 4096;
constexpr int S_  = 32;     // stride of the strided convs
constexpr int G3  = 1536;   // 3*M

// ---------------------------------------------------------------------------
// Kernel 1: front end. One block per batch row, 512 threads (one per output j).
// ---------------------------------------------------------------------------
__global__ __launch_bounds__(512) void k_front(
    const float* __restrict__ st1, const float* __restrict__ ht1,
    const float* __restrict__ zt, const int* __restrict__ da_t,
    const float* __restrict__ w_st1, const float* __restrict__ b_st1,
    const float* __restrict__ w_st12, const float* __restrict__ b_st12,
    const float* __restrict__ w_mt1, const float* __restrict__ b_mt1,
    const float* __restrict__ w_xt, const float* __restrict__ b_xt,
    float* __restrict__ xt_out, float* __restrict__ ht1c_out)
{
    __shared__ float sm[2 * M_];   // Mt1 = [Mt1_0 | ht1]
    const int b = blockIdx.x;
    const int j = threadIdx.x;

    const float* srow = st1 + (size_t)b * N_;

    const float w0 = w_st1[0], w1 = w_st1[1], w2 = w_st1[2], w3 = w_st1[3], w4 = w_st1[4];
    const float bs = b_st1[0];

    // conv5 (pad 2) evaluated at p = 32j and p+1 -> needs st1[p-2 .. p+3]
    const int p = S_ * j;
    float x[6];
    if (j > 0 && j < M_ - 1) {
        const float2 a = *(const float2*)(srow + p - 2);
        const float2 c = *(const float2*)(srow + p);
        const float2 d = *(const float2*)(srow + p + 2);
        x[0] = a.x; x[1] = a.y; x[2] = c.x; x[3] = c.y; x[4] = d.x; x[5] = d.y;
    } else {
        #pragma unroll
        for (int k = 0; k < 6; ++k) {
            int ix = p - 2 + k;
            x[k] = (ix >= 0 && ix < N_) ? srow[ix] : 0.0f;
        }
    }
    float y0 = bs;
    y0 = fmaf(x[0], w0, y0); y0 = fmaf(x[1], w1, y0); y0 = fmaf(x[2], w2, y0);
    y0 = fmaf(x[3], w3, y0); y0 = fmaf(x[4], w4, y0);
    float y1 = bs;
    y1 = fmaf(x[1], w0, y1); y1 = fmaf(x[2], w1, y1); y1 = fmaf(x[3], w2, y1);
    y1 = fmaf(x[4], w3, y1); y1 = fmaf(x[5], w4, y1);

    const float m0 = fmaf(y0, w_st12[0], fmaf(y1, w_st12[1], b_st12[0]));
    sm[j]      = m0;
    sm[M_ + j] = ht1[(size_t)b * M_ + j];

    const float daf = (float)da_t[b];
    const float* zrow = zt + (size_t)b * (N_ - 1);
    const float u0 = zrow[S_ * j];
    const float u1 = (j == M_ - 1) ? daf : zrow[S_ * j + 1];
    xt_out[(size_t)b * M_ + j] = fmaf(u0, w_xt[0], fmaf(u1, w_xt[1], b_xt[0]));

    __syncthreads();

    const int q = 2 * j;
    float vm1 = 0.0f, v0, vp1 = 0.0f;
    if (q - 1 >= 0) { float t = sm[q - 1]; vm1 = t > 0.0f ? t : 0.0f; }
    { float t = sm[q]; v0 = t > 0.0f ? t : 0.0f; }
    if (q + 1 < 2 * M_) { float t = sm[q + 1]; vp1 = t > 0.0f ? t : 0.0f; }
    const float hv = fmaf(vm1, w_mt1[0], fmaf(v0, w_mt1[1], fmaf(vp1, w_mt1[2], b_mt1[0])));
    ht1c_out[(size_t)b * M_ + j] = hv;
}

// ---------------------------------------------------------------------------
// Kernel 2: f32 GEMM (R3 tile), K-split zs=4 for occupancy (measured best).
// R9 PMC: VALUBusy 41%, Occ 14% at 384 blocks (latency-bound).
// zs=4 -> 768 blocks = 3 blocks/CU uniform = 12 waves/CU -> 36.8us total (R10).
// zs=8 regressed (37.9, R11): kper=64 -> ramp overhead + extra partial traffic.
// BM=64 x BN=64 x BK=32, 256 threads, 4x4 frag, both fragments ds_read_b128.
// Partials g[z][which][B][G3] summed in the tail in fixed z-order.
// ---------------------------------------------------------------------------
constexpr int BMt = 64;
constexpr int BNt = 64;
constexpr int BKt = 32;
constexpr size_t GPART = (size_t)B_ * G3;   // elements per partial matrix

__global__ __launch_bounds__(256) void k_gemm(
    const float* __restrict__ xt, const float* __restrict__ Ht1c,
    const float* __restrict__ W_ih, const float* __restrict__ W_hh,
    float* __restrict__ g, int kper)
{
    __shared__ __align__(16) float As[BKt][BMt + 4];  // row = 272B (17x16B)
    __shared__ __align__(16) float Ws[BKt][BNt + 4];

    const int t = threadIdx.x;
    const int bm0 = blockIdx.y * BMt;
    const int z = blockIdx.z;
    int n0 = blockIdx.x * BNt;

    const float* A;
    const float* W;
    float* out;
    if (n0 < G3) { A = xt;   W = W_ih; out = g + (size_t)(2 * z + 0) * GPART; }
    else         { A = Ht1c; W = W_hh; out = g + (size_t)(2 * z + 1) * GPART; n0 -= G3; }

    // staging coords: 64 rows x 32 k per tile, 2 float4 per thread
    const int srow = t >> 2;          // 0..63
    const int sc4  = t & 3;           // 0..3 (k-chunk)

    // fragment coords
    const int tm = (t & 15) * 4;      // 4 batch rows
    const int tn = (t >> 4) * 4;      // 4 output cols

    float acc[4][4];
    #pragma unroll
    for (int i = 0; i < 4; ++i)
        #pragma unroll
        for (int jj = 0; jj < 4; ++jj) acc[i][jj] = 0.0f;

    const int kbeg = z * kper;
    const int kend = kbeg + kper;

    for (int k0 = kbeg; k0 < kend; k0 += BKt) {
        {
            const float* ap = A + (size_t)(bm0 + srow) * M_ + k0 + 4 * sc4;
            const float4 f0 = *(const float4*)ap;
            const float4 f1 = *(const float4*)(ap + 16);
            As[4 * sc4 + 0][srow] = f0.x; As[4 * sc4 + 1][srow] = f0.y;
            As[4 * sc4 + 2][srow] = f0.z; As[4 * sc4 + 3][srow] = f0.w;
            As[16 + 4 * sc4 + 0][srow] = f1.x; As[16 + 4 * sc4 + 1][srow] = f1.y;
            As[16 + 4 * sc4 + 2][srow] = f1.z; As[16 + 4 * sc4 + 3][srow] = f1.w;
        }
        {
            const float* wp = W + (size_t)(n0 + srow) * M_ + k0 + 4 * sc4;
            const float4 g0 = *(const float4*)wp;
            const float4 g1 = *(const float4*)(wp + 16);
            Ws[4 * sc4 + 0][srow] = g0.x; Ws[4 * sc4 + 1][srow] = g0.y;
            Ws[4 * sc4 + 2][srow] = g0.z; Ws[4 * sc4 + 3][srow] = g0.w;
            Ws[16 + 4 * sc4 + 0][srow] = g1.x; Ws[16 + 4 * sc4 + 1][srow] = g1.y;
            Ws[16 + 4 * sc4 + 2][srow] = g1.z; Ws[16 + 4 * sc4 + 3][srow] = g1.w;
        }
        __syncthreads();

        #pragma unroll
        for (int k = 0; k < BKt; ++k) {
            const float4 a = *(const float4*)&As[k][tm];   // ds_read_b128
            const float4 w = *(const float4*)&Ws[k][tn];   // ds_read_b128
            acc[0][0] = fmaf(a.x, w.x, acc[0][0]); acc[0][1] = fmaf(a.x, w.y, acc[0][1]);
            acc[0][2] = fmaf(a.x, w.z, acc[0][2]); acc[0][3] = fmaf(a.x, w.w, acc[0][3]);
            acc[1][0] = fmaf(a.y, w.x, acc[1][0]); acc[1][1] = fmaf(a.y, w.y, acc[1][1]);
            acc[1][2] = fmaf(a.y, w.z, acc[1][2]); acc[1][3] = fmaf(a.y, w.w, acc[1][3]);
            acc[2][0] = fmaf(a.z, w.x, acc[2][0]); acc[2][1] = fmaf(a.z, w.y, acc[2][1]);
            acc[2][2] = fmaf(a.z, w.z, acc[2][2]); acc[2][3] = fmaf(a.z, w.w, acc[2][3]);
            acc[3][0] = fmaf(a.w, w.x, acc[3][0]); acc[3][1] = fmaf(a.w, w.y, acc[3][1]);
            acc[3][2] = fmaf(a.w, w.z, acc[3][2]); acc[3][3] = fmaf(a.w, w.w, acc[3][3]);
        }
        __syncthreads();
    }

    #pragma unroll
    for (int i = 0; i < 4; ++i) {
        float4 o;
        o.x = acc[i][0]; o.y = acc[i][1]; o.z = acc[i][2]; o.w = acc[i][3];
        *(float4*)&out[(size_t)(bm0 + tm + i) * G3 + n0 + tn] = o;  // 16B-aligned
    }
}

// ---------------------------------------------------------------------------
// Kernel 3 (fused tail, R10 version): GRU gates + ht + it/ct reductions, then
// the row stream st[b,i] = (da+i < N ? st1[b, da+i] : 0)*ct + emb[it, i].
// One block per batch row, 1024 threads (gates on threads 0..511).
// g layout: [z][which][B][G3]; zs partial sums added in fixed z-order.
// ---------------------------------------------------------------------------
__global__ __launch_bounds__(1024) void k_tail(
    const float* __restrict__ g, int zs,
    const float* __restrict__ b_ih, const float* __restrict__ b_hh,
    const float* __restrict__ Ht1c, const int* __restrict__ da_t,
    const float* __restrict__ w_lht, const float* __restrict__ b_lht,
    const float* __restrict__ w_lct, const float* __restrict__ b_lct,
    const float* __restrict__ st1, const float* __restrict__ emb,
    float* __restrict__ ht_out, float* __restrict__ st_out)
{
    __shared__ float red1[8], red2[8];
    __shared__ float s_ct;
    __shared__ int   s_it;

    const int b = blockIdx.x;
    const int o = threadIdx.x;
    const int da = da_t[b];

    if (o < M_) {
        float ir = 0.f, iz = 0.f, inn = 0.f, hr = 0.f, hz = 0.f, hn = 0.f;
        for (int zz = 0; zz < zs; ++zz) {
            const float* gib = g + (size_t)(2 * zz + 0) * GPART + (size_t)b * G3;
            const float* ghb = g + (size_t)(2 * zz + 1) * GPART + (size_t)b * G3;
            ir  += gib[o];
            iz  += gib[M_ + o];
            inn += gib[2 * M_ + o];
            hr  += ghb[o];
            hz  += ghb[M_ + o];
            hn  += ghb[2 * M_ + o];
        }
        ir  += b_ih[o];
        iz  += b_ih[M_ + o];
        inn += b_ih[2 * M_ + o];
        hr  += b_hh[o];
        hz  += b_hh[M_ + o];
        hn  += b_hh[2 * M_ + o];

        const float r  = 1.0f / (1.0f + expf(-(ir + hr)));
        const float z  = 1.0f / (1.0f + expf(-(iz + hz)));
        const float n_ = tanhf(fmaf(r, hn, inn));
        const float hprev = Ht1c[(size_t)b * M_ + o];
        const float h = (1.0f - z) * n_ + z * hprev;

        ht_out[(size_t)b * M_ + o] = h;

        float p1 = h * w_lht[o];
        float p2 = h * w_lct[o];
        #pragma unroll
        for (int off = 32; off > 0; off >>= 1) {
            p1 += __shfl_down(p1, off);
            p2 += __shfl_down(p2, off);
        }
        const int wid = o >> 6, lane = o & 63;
        if (lane == 0) { red1[wid] = p1; red2[wid] = p2; }
    }
    __syncthreads();
    if (o == 0) {
        float s1 = 0.0f, s2 = 0.0f;
        #pragma unroll
        for (int i = 0; i < 8; ++i) { s1 += red1[i]; s2 += red2[i]; }
        const float a1 = s1 + b_lht[0];
        const float sg1 = 1.0f / (1.0f + expf(-a1));
        s_it = (int)floorf((float)(V_ - 1) * sg1);

        const float daf = (float)da;
        const float a2 = s2 + daf * w_lct[M_] + b_lct[0];
        s_ct = 1.0f / (1.0f + expf(-a2));
    }
    __syncthreads();

    const int   it = s_it;
    const float ct = s_ct;

    const float* er = emb + (size_t)it * N_;
    const float* sr = st1 + (size_t)b * N_;
    float* orow     = st_out + (size_t)b * N_;

    // float2 streaming: N even (8177 pairs); rows 8B-aligned.
    const float2* er2 = (const float2*)er;
    float2* orow2     = (float2*)orow;
    constexpr int H = N_ / 2;

    if ((da & 1) == 0) {
        for (int k = o; k < H; k += 1024) {
            const int i = 2 * k;
            const int idx = da + i;
            float2 sv;
            if (idx + 1 < N_)      sv = *(const float2*)(sr + idx);
            else if (idx < N_)     { sv.x = sr[idx]; sv.y = 0.0f; }
            else                   { sv.x = 0.0f; sv.y = 0.0f; }
            const float2 e = er2[k];
            float2 ov;
            ov.x = fmaf(sv.x, ct, e.x);
            ov.y = fmaf(sv.y, ct, e.y);
            orow2[k] = ov;
        }
    } else {
        for (int k = o; k < H; k += 1024) {
            const int i = 2 * k;
            const int idx = da + i;
            float2 sv;
            sv.x = (idx < N_)     ? sr[idx]     : 0.0f;
            sv.y = (idx + 1 < N_) ? sr[idx + 1] : 0.0f;
            const float2 e = er2[k];
            float2 ov;
            ov.x = fmaf(sv.x, ct, e.x);
            ov.y = fmaf(sv.y, ct, e.y);
            orow2[k] = ov;
        }
    }
}

// ---------------------------------------------------------------------------
extern "C" void kernel_launch(void* const* d_in, const int* in_sizes, int n_in,
                              void* d_out, int out_size, void* d_ws, size_t ws_size,
                              hipStream_t stream)
{
    const float* st1   = (const float*)d_in[0];
    const float* ht1   = (const float*)d_in[1];
    const float* zt    = (const float*)d_in[2];
    const int*   da_t  = (const int*)d_in[3];
    const float* w_st1 = (const float*)d_in[4];
    const float* b_st1 = (const float*)d_in[5];
    const float* w_st12= (const float*)d_in[6];
    const float* b_st12= (const float*)d_in[7];
    const float* w_mt1 = (const float*)d_in[8];
    const float* b_mt1 = (const float*)d_in[9];
    const float* w_xt  = (const float*)d_in[10];
    const float* b_xt  = (const float*)d_in[11];
    const float* W_ih  = (const float*)d_in[12];
    const float* W_hh  = (const float*)d_in[13];
    const float* b_ih  = (const float*)d_in[14];
    const float* b_hh  = (const float*)d_in[15];
    const float* w_lht = (const float*)d_in[16];
    const float* b_lht = (const float*)d_in[17];
    const float* w_lct = (const float*)d_in[18];
    const float* b_lct = (const float*)d_in[19];
    const float* emb   = (const float*)d_in[20];

    float* st_out = (float*)d_out;                      // [B, N]
    float* ht_out = (float*)d_out + (size_t)B_ * N_;    // [B, M]

    // workspace layout (floats): xt, Ht1c, g[z][2][B][G3]
    float* ws   = (float*)d_ws;
    float* xt   = ws;                         // B*M
    float* Ht1c = xt + (size_t)B_ * M_;       // B*M
    float* g    = Ht1c + (size_t)B_ * M_;     // zs*2*B*G3

    const size_t base = 2 * (size_t)B_ * M_ * sizeof(float);
    int zs = 1;
    if (ws_size >= base + 8 * GPART * sizeof(float))      zs = 4;
    else if (ws_size >= base + 4 * GPART * sizeof(float)) zs = 2;
    const int kper = M_ / zs;

    k_front<<<dim3(B_), dim3(M_), 0, stream>>>(
        st1, ht1, zt, da_t, w_st1, b_st1, w_st12, b_st12,
        w_mt1, b_mt1, w_xt, b_xt, xt, Ht1c);

    k_gemm<<<dim3(2 * G3 / BNt, B_ / BMt, zs), dim3(256), 0, stream>>>(
        xt, Ht1c, W_ih, W_hh, g, kper);

    k_tail<<<dim3(B_), dim3(1024), 0, stream>>>(
        g, zs, b_ih, b_hh, Ht1c, da_t,
        w_lht, b_lht, w_lct, b_lct, st1, emb, ht_out, st_out);
}